// Round 3
// baseline (925.249 us; speedup 1.0000x reference)
//
#include <hip/hip_runtime.h>
#include <cfloat>

// NearestNeighborGraph: S=16, N=2048, D=64, K=16.
// Round-3: LDS-broadcast feed (per-wave double-buffered staging, barrier-free
// main loop), 2 rows/lane (128 fmac per 16 broadcast ds_read_b128), 8-wave
// blocks (1 block/CU, 2 waves/SIMD), deferred insert + peel-16 bootstrap.
// d2 arithmetic bit-identical to rounds 1-2 (same chains, same x2 kernel).

constexpr int NS = 16, NP = 2048, ND = 64, KK = 16;
constexpr int NW  = 8;            // waves per block
constexpr int NT  = NW * 64;      // 512 threads
constexpr int JW  = NP / NW;      // 256 j per wave
constexpr int CH  = 4;            // j-rows per staged chunk (1 KB)
constexpr int NCH = JW / CH;      // 64 chunks
constexpr int BUF = 4;            // candidate slots per lane per row

__global__ void x2_kernel(const float* __restrict__ h, float* __restrict__ x2)
{
    int g = blockIdx.x * 256 + threadIdx.x;          // 0 .. NS*NP-1
    const float4* row = (const float4*)(h + (size_t)g * ND);
    int ph = g & 15;                                  // == j&15 within sample
    float a0 = 0.f, a1 = 0.f, a2 = 0.f, a3 = 0.f;
    #pragma unroll
    for (int k = 0; k < 16; ++k) {
        float4 v = row[(k + ph) & 15];               // round-1's rotated order
        a0 = fmaf(v.x, v.x, a0); a1 = fmaf(v.y, v.y, a1);
        a2 = fmaf(v.z, v.z, a2); a3 = fmaf(v.w, v.w, a3);
    }
    x2[g] = (a0 + a1) + (a2 + a3);
}

__device__ __forceinline__ void insert16(float (&d)[KK], int (&ix)[KK],
                                         float v, int j)
{
    #pragma unroll
    for (int p = KK - 1; p > 0; --p) {
        bool sh = v < d[p - 1];
        bool he = v < d[p];
        float nd = sh ? d[p - 1] : (he ? v : d[p]);
        int   ni = sh ? ix[p - 1] : (he ? j : ix[p]);
        d[p] = nd; ix[p] = ni;
    }
    if (v < d[0]) { d[0] = v; ix[0] = j; }
}

// stable odd-even transposition sort (strict < keeps lower index first on ties)
__device__ __forceinline__ void sort16(float (&d)[KK], int (&ix)[KK])
{
    #pragma unroll
    for (int pass = 0; pass < KK; ++pass) {
        #pragma unroll
        for (int k = (pass & 1); k + 1 < KK; k += 2) {
            bool sw = d[k + 1] < d[k];
            float td = d[k];     int ti = ix[k];
            float tu = d[k + 1]; int tj = ix[k + 1];
            d[k]     = sw ? tu : td;  ix[k]     = sw ? tj : ti;
            d[k + 1] = sw ? td : tu;  ix[k + 1] = sw ? ti : tj;
        }
    }
}

// two dots against one broadcast j-vector; chain order identical to rounds 1-2
__device__ __forceinline__ void dot2(const float* __restrict__ cvp,
                                     const float4 (&A)[16], const float4 (&B)[16],
                                     float& da, float& db)
{
    const float4* cv = (const float4*)cvp;
    float a0 = 0.f, a1 = 0.f, a2 = 0.f, a3 = 0.f;
    float b0 = 0.f, b1 = 0.f, b2 = 0.f, b3 = 0.f;
    #pragma unroll
    for (int k = 0; k < 16; ++k) {
        float4 c = cv[k];
        a0 = fmaf(A[k].x, c.x, a0); a1 = fmaf(A[k].y, c.y, a1);
        a2 = fmaf(A[k].z, c.z, a2); a3 = fmaf(A[k].w, c.w, a3);
        b0 = fmaf(B[k].x, c.x, b0); b1 = fmaf(B[k].y, c.y, b1);
        b2 = fmaf(B[k].z, c.z, b2); b3 = fmaf(B[k].w, c.w, b3);
    }
    da = (a0 + a1) + (a2 + a3);
    db = (b0 + b1) + (b2 + b3);
}

__global__ __launch_bounds__(NT, 2)
void knn_main(const float* __restrict__ h, const float* __restrict__ x2g,
              float* __restrict__ out)
{
    // LDS carve: stage 16 KB | x2 8 KB | push-d 16 KB | push-i 16 KB = 56 KB.
    // merge tree aliases the push region (dead after final drain).
    __shared__ __align__(16) float smem[14336];
    float* stage = smem;                   // 4096 floats: 8 waves x 2 bufs x 256
    float* ldsx2 = smem + 4096;            // 2048 floats
    float* pbufd = smem + 6144;            // 4096 floats: [2 rows][BUF][NT]
    int*   pbufi = (int*)(smem + 10240);   // 4096 ints

    const int t  = threadIdx.x;
    const int ln = t & 63;
    const int q  = t >> 6;                 // wave id = j-eighth
    const int s  = blockIdx.x >> 4;
    const int rb = blockIdx.x & 15;
    const int rowA = rb * 128 + ln;
    const int rowB = rowA + 64;
    const float* __restrict__ hs = h + (size_t)s * NP * ND;

    // stage the sample's x2 (broadcast-readable later)
    for (int i = t; i < NP; i += NT) ldsx2[i] = x2g[s * NP + i];

    // own rows into registers (128 VGPRs)
    float4 A[16], B[16];
    {
        const float4* ra = (const float4*)(hs + rowA * ND);
        const float4* rp = (const float4*)(hs + rowB * ND);
        #pragma unroll
        for (int k = 0; k < 16; ++k) { A[k] = ra[k]; B[k] = rp[k]; }
    }
    float x2A, x2B;
    {
        float a0 = 0.f, a1 = 0.f, a2 = 0.f, a3 = 0.f;
        #pragma unroll
        for (int k = 0; k < 16; ++k) {
            a0 = fmaf(A[k].x, A[k].x, a0); a1 = fmaf(A[k].y, A[k].y, a1);
            a2 = fmaf(A[k].z, A[k].z, a2); a3 = fmaf(A[k].w, A[k].w, a3);
        }
        x2A = (a0 + a1) + (a2 + a3);
    }
    {
        float a0 = 0.f, a1 = 0.f, a2 = 0.f, a3 = 0.f;
        #pragma unroll
        for (int k = 0; k < 16; ++k) {
            a0 = fmaf(B[k].x, B[k].x, a0); a1 = fmaf(B[k].y, B[k].y, a1);
            a2 = fmaf(B[k].z, B[k].z, a2); a3 = fmaf(B[k].w, B[k].w, a3);
        }
        x2B = (a0 + a1) + (a2 + a3);
    }

    const int jbase = q * JW;
    float* stW = stage + q * 512;                       // wave-private 2 KB
    const float* gbase = hs + (size_t)jbase * ND + ln * 4;

    // staging prologue: chunk 0 into buf0, chunk 1 loaded
    float4 v0 = *(const float4*)(gbase);
    *(float4*)(stW + ln * 4) = v0;
    float4 vn = *(const float4*)(gbase + (size_t)CH * ND);

    __syncthreads();   // x2 staging visible

    float distA[KK], distB[KK];
    int   idxA[KK],  idxB[KK];

    // ---- peel: first 16 j -> direct stores, then stable sort ----
    #pragma unroll
    for (int c = 0; c < 4; ++c) {
        const float4 xc = ((const float4*)ldsx2)[(jbase >> 2) + c];
        const float* bufp = stW + (c & 1) * 256;
        #pragma unroll
        for (int jj = 0; jj < CH; ++jj) {
            float da, db;
            dot2(bufp + jj * 64, A, B, da, db);
            float xj = (jj == 0) ? xc.x : (jj == 1) ? xc.y : (jj == 2) ? xc.z : xc.w;
            distA[c * CH + jj] = fmaf(-2.f, da, x2A + xj);
            distB[c * CH + jj] = fmaf(-2.f, db, x2B + xj);
            idxA[c * CH + jj] = jbase + c * CH + jj;
            idxB[c * CH + jj] = jbase + c * CH + jj;
        }
        *(float4*)(stW + ((c + 1) & 1) * 256 + ln * 4) = vn;
        int nc = (c + 2 < NCH) ? (c + 2) : (NCH - 1);
        vn = *(const float4*)(gbase + (size_t)nc * CH * ND);
    }
    sort16(distA, idxA);
    sort16(distB, idxB);

    int cntA = 0, cntB = 0;
    auto drain = [&]() {
        #pragma unroll 1
        for (int k = 0; k < BUF; ++k) {
            if (!__any((k < cntA) | (k < cntB))) break;
            float da = pbufd[k * NT + t];         int ja = pbufi[k * NT + t];
            insert16(distA, idxA, (k < cntA) ? da : FLT_MAX, ja);
            float db = pbufd[(BUF + k) * NT + t]; int jb = pbufi[(BUF + k) * NT + t];
            insert16(distB, idxB, (k < cntB) ? db : FLT_MAX, jb);
        }
        cntA = 0; cntB = 0;
    };

    // ---- main loop: chunks 4..63, barrier-free double-buffered staging ----
    for (int c = 4; c < NCH; ++c) {
        const float4 xc = ((const float4*)ldsx2)[(jbase >> 2) + c];
        const float* bufp = stW + (c & 1) * 256;
        #pragma unroll
        for (int jj = 0; jj < CH; ++jj) {
            float da, db;
            dot2(bufp + jj * 64, A, B, da, db);
            float xj = (jj == 0) ? xc.x : (jj == 1) ? xc.y : (jj == 2) ? xc.z : xc.w;
            float d2a = fmaf(-2.f, da, x2A + xj);
            float d2b = fmaf(-2.f, db, x2B + xj);
            int j = jbase + c * CH + jj;
            pbufd[cntA * NT + t] = d2a;          pbufi[cntA * NT + t] = j;
            cntA += (d2a < distA[KK - 1]) ? 1 : 0;
            pbufd[(BUF + cntB) * NT + t] = d2b;  pbufi[(BUF + cntB) * NT + t] = j;
            cntB += (d2b < distB[KK - 1]) ? 1 : 0;
            if (__any((cntA == BUF) | (cntB == BUF))) drain();
        }
        if (c + 1 < NCH) *(float4*)(stW + ((c + 1) & 1) * 256 + ln * 4) = vn;
        if (c + 2 < NCH) vn = *(const float4*)(gbase + (size_t)(c + 2) * CH * ND);
    }
    drain();

    // ---- 3-level merge tree through LDS (aliases dead push buffers) ----
    __syncthreads();
    float* md = smem + 6144;               // 4 regions x 64 lanes x 16
    int*   mi = (int*)(smem + 10240);
    #pragma unroll 1
    for (int lvl = 0; lvl < 3; ++lvl) {
        const int step = 1 << lvl;
        const int m    = (step << 1) - 1;
        const bool pub = (q & m) == step;
        const bool con = (q & m) == 0;
        const int reg  = q >> (lvl + 1);
        if (pub) {
            #pragma unroll
            for (int k = 0; k < KK; ++k) {
                md[(reg * 64 + ln) * KK + k] = distA[k];
                mi[(reg * 64 + ln) * KK + k] = idxA[k];
            }
        }
        __syncthreads();
        if (con) {
            #pragma unroll 1
            for (int k = 0; k < KK; ++k)
                insert16(distA, idxA, md[(reg * 64 + ln) * KK + k],
                                      mi[(reg * 64 + ln) * KK + k]);
        }
        __syncthreads();
        if (pub) {
            #pragma unroll
            for (int k = 0; k < KK; ++k) {
                md[(reg * 64 + ln) * KK + k] = distB[k];
                mi[(reg * 64 + ln) * KK + k] = idxB[k];
            }
        }
        __syncthreads();
        if (con) {
            #pragma unroll 1
            for (int k = 0; k < KK; ++k)
                insert16(distB, idxB, md[(reg * 64 + ln) * KK + k],
                                      mi[(reg * 64 + ln) * KK + k]);
        }
        __syncthreads();
    }

    // ---- output (wave 0 holds the complete lists for rows rowA, rowB) ----
    if (q == 0) {
        const int off = s * NP;
        {
            const size_t rg = (size_t)off + rowA;
            float* o0 = out + rg * KK;
            float* o1 = out + (size_t)NS * NP * KK + rg * KK;
            float* o2 = out + (size_t)2 * NS * NP * KK + rg * KK;
            #pragma unroll
            for (int k = 0; k < KK; ++k) o0[k] = distA[k];
            #pragma unroll
            for (int k = 0; k < KK; ++k) o1[k] = (float)(idxA[k] + off);
            #pragma unroll
            for (int k = 0; k < KK; ++k) o2[k] = (float)(off + rowA);
        }
        {
            const size_t rg = (size_t)off + rowB;
            float* o0 = out + rg * KK;
            float* o1 = out + (size_t)NS * NP * KK + rg * KK;
            float* o2 = out + (size_t)2 * NS * NP * KK + rg * KK;
            #pragma unroll
            for (int k = 0; k < KK; ++k) o0[k] = distB[k];
            #pragma unroll
            for (int k = 0; k < KK; ++k) o1[k] = (float)(idxB[k] + off);
            #pragma unroll
            for (int k = 0; k < KK; ++k) o2[k] = (float)(off + rowB);
        }
    }
}

extern "C" void kernel_launch(void* const* d_in, const int* in_sizes, int n_in,
                              void* d_out, int out_size, void* d_ws, size_t ws_size,
                              hipStream_t stream)
{
    const float* h = (const float*)d_in[0];
    float* x2  = (float*)d_ws;            // NS*NP floats = 128 KB scratch
    float* out = (float*)d_out;
    hipLaunchKernelGGL(x2_kernel, dim3(NS * NP / 256), dim3(256), 0, stream, h, x2);
    hipLaunchKernelGGL(knn_main,  dim3(NS * 16),       dim3(NT),  0, stream, h, x2, out);
}